// Round 8
// baseline (428.994 us; speedup 1.0000x reference)
//
#include <hip/hip_runtime.h>

#define HID 128
#define BSHIFT 10            // 1024 dst-nodes per bucket
#define BCAP 20480           // bucket capacity (mean 16.3K, sigma ~127 -> 32 sigma)

typedef _Float16 half8 __attribute__((ext_vector_type(8)));
typedef _Float16 half4v __attribute__((ext_vector_type(4)));
typedef float f32x4 __attribute__((ext_vector_type(4)));

// ---------------- graph build: two-pass binned scatter ----------------

__global__ __launch_bounds__(256) void zero_i32(int* __restrict__ p, int n) {
  int i = blockIdx.x * 256 + threadIdx.x;
  if (i < n) p[i] = 0;
}

__global__ __launch_bounds__(256) void bin_edges(const int* __restrict__ ei,
                                                 int* __restrict__ gcur,
                                                 int2* __restrict__ buf,
                                                 int E, int NB) {
  __shared__ int bcnt[128];
  __shared__ int bbase[128];
  const int tid = threadIdx.x;

  for (int chunk = blockIdx.x * 2048; chunk < E; chunk += gridDim.x * 2048) {
    if (tid < NB) bcnt[tid] = 0;
    __syncthreads();
    int s[8], d[8], slot[8], b[8];
#pragma unroll
    for (int j = 0; j < 8; ++j) {
      int e = chunk + tid + j * 256;
      if (e < E) {
        s[j] = ei[e];
        d[j] = ei[E + e];
        b[j] = d[j] >> BSHIFT;
        slot[j] = atomicAdd(&bcnt[b[j]], 1);
      } else {
        b[j] = -1;
      }
    }
    __syncthreads();
    if (tid < NB && bcnt[tid] > 0) bbase[tid] = atomicAdd(&gcur[tid], bcnt[tid]);
    __syncthreads();
#pragma unroll
    for (int j = 0; j < 8; ++j) {
      if (b[j] >= 0) {
        int pos = bbase[b[j]] + slot[j];
        if (pos < BCAP) buf[(size_t)b[j] * BCAP + pos] = make_int2(s[j], d[j]);
      }
    }
    __syncthreads();
  }
}

__global__ __launch_bounds__(256) void scatter_pad(const int2* __restrict__ buf,
                                                   const int* __restrict__ gcur,
                                                   int* __restrict__ colpad,
                                                   int* __restrict__ cnt,
                                                   float* __restrict__ dinv, int N) {
  __shared__ int lcnt[1 << BSHIFT];
  const int b = blockIdx.x;
  const int base = b << BSHIFT;
  const int tid = threadIdx.x;
  for (int i = tid; i < (1 << BSHIFT); i += 256) lcnt[i] = 0;
  __syncthreads();

  int ne = gcur[b];
  if (ne > BCAP) ne = BCAP;
  const int2* __restrict__ bb = buf + (size_t)b * BCAP;
  for (int i = tid; i < ne; i += 256) {
    int2 p = bb[i];
    int pos = atomicAdd(&lcnt[p.y - base], 1);
    if (pos < 64) colpad[(size_t)p.y * 64 + pos] = p.x;
  }
  __syncthreads();
  for (int i = tid; i < (1 << BSHIFT); i += 256) {
    int n = base + i;
    if (n < N) {
      int c = lcnt[i];
      cnt[n] = c;
      dinv[n] = rsqrtf((float)(c + 1));
    }
  }
}

// ---------------- converts ----------------

__global__ __launch_bounds__(256) void cvt_w2(const float* __restrict__ a, int na,
                                              const float* __restrict__ b, int nb,
                                              _Float16* __restrict__ oa,
                                              _Float16* __restrict__ ob) {
  int i = blockIdx.x * 256 + threadIdx.x;
  if (i < na) oa[i] = (_Float16)a[i];
  else if (i < na + nb) ob[i - na] = (_Float16)b[i - na];
}

// x fp32 -> f16, 8 elements per thread-iter, grid-stride
__global__ __launch_bounds__(256) void cvt_x(const float* __restrict__ in,
                                             _Float16* __restrict__ out, int n8) {
  int stride = gridDim.x * 256;
  for (int i = blockIdx.x * 256 + threadIdx.x; i < n8; i += stride) {
    const float* src = in + (size_t)i * 8;
    float4 f0 = *(const float4*)(src);
    float4 f1 = *(const float4*)(src + 4);
    half8 h;
    h[0] = (_Float16)f0.x; h[1] = (_Float16)f0.y;
    h[2] = (_Float16)f0.z; h[3] = (_Float16)f0.w;
    h[4] = (_Float16)f1.x; h[5] = (_Float16)f1.y;
    h[6] = (_Float16)f1.z; h[7] = (_Float16)f1.w;
    *(half8*)(out + (size_t)i * 8) = h;
  }
}

// ---------------- MFMA GEMM (2-phase reg-staged pipeline) ----------------
// out[N][128] = A[N][K] @ W[128][K]^T ; A,W f16; epilogue scale/bias/relu; out f16.

template <int K>
__global__ __launch_bounds__(256) void gemm_mfma(const _Float16* __restrict__ Ah,
                                                 const _Float16* __restrict__ Wh,
                                                 const float* __restrict__ bias,
                                                 const float* __restrict__ rowscale,
                                                 _Float16* __restrict__ out,
                                                 int N, int do_relu) {
  // 128x128 tile, BK=64.  LDS tiles f16, XOR-swizzled: byte ^= ((row&7)<<4)
  __shared__ __align__(16) char As[128 * 64 * 2];
  __shared__ __align__(16) char Bs[128 * 64 * 2];

  const int tid = threadIdx.x;
  const int lane = tid & 63;
  const int wave = tid >> 6;
  const int wr = wave >> 1, wc = wave & 1;  // 2x2 wave grid, each 64x64
  const int row0 = blockIdx.x * 128;

  // staging addresses (constant across k-steps); all indices compile-time unrolled
  int stbyte[4];
  const _Float16* asrc[4];
  const _Float16* bsrc[4];
#pragma unroll
  for (int i = 0; i < 4; ++i) {
    int chunk = tid + i * 256;
    int r = chunk >> 3, q = chunk & 7;
    int gr = row0 + r;
    if (gr >= N) gr = N - 1;  // clamp (stores masked later)
    stbyte[i] = (r << 7) | ((q ^ (r & 7)) << 4);
    asrc[i] = Ah + (size_t)gr * K + q * 8;
    bsrc[i] = Wh + (size_t)r * K + q * 8;  // B row c == r
  }

  half8 ga[4], gb[4];
#pragma unroll
  for (int i = 0; i < 4; ++i) {
    ga[i] = *(const half8*)(asrc[i]);
    gb[i] = *(const half8*)(bsrc[i]);
  }

  f32x4 acc[4][4] = {};

  for (int k0 = 0; k0 < K; k0 += 64) {
    __syncthreads();  // previous MFMA phase done reading LDS
#pragma unroll
    for (int i = 0; i < 4; ++i) {
      *(half8*)(As + stbyte[i]) = ga[i];
      *(half8*)(Bs + stbyte[i]) = gb[i];
    }
    if (k0 + 64 < K) {  // issue next-tile loads; they fly through MFMA below
#pragma unroll
      for (int i = 0; i < 4; ++i) {
        ga[i] = *(const half8*)(asrc[i] + k0 + 64);
        gb[i] = *(const half8*)(bsrc[i] + k0 + 64);
      }
    }
    __syncthreads();

#pragma unroll
    for (int ks = 0; ks < 2; ++ks) {
      half8 a[4], b[4];
#pragma unroll
      for (int mi = 0; mi < 4; ++mi) {
        int r = wr * 64 + mi * 16 + (lane & 15);
        int q = ks * 4 + (lane >> 4);
        a[mi] = *(const half8*)(As + ((r << 7) | ((q ^ (r & 7)) << 4)));
      }
#pragma unroll
      for (int ni = 0; ni < 4; ++ni) {
        int c = wc * 64 + ni * 16 + (lane & 15);
        int q = ks * 4 + (lane >> 4);
        b[ni] = *(const half8*)(Bs + ((c << 7) | ((q ^ (c & 7)) << 4)));
      }
#pragma unroll
      for (int mi = 0; mi < 4; ++mi)
#pragma unroll
        for (int ni = 0; ni < 4; ++ni)
          acc[mi][ni] = __builtin_amdgcn_mfma_f32_16x16x32_f16(a[mi], b[ni], acc[mi][ni], 0, 0, 0);
    }
  }

  // epilogue: col = lane&15 (+16*ni+64*wc), row = (lane>>4)*4 + j (+16*mi+64*wr)
  const int cbase = wc * 64 + (lane & 15);
  const int rsub = (lane >> 4) * 4;
#pragma unroll
  for (int mi = 0; mi < 4; ++mi) {
#pragma unroll
    for (int j = 0; j < 4; ++j) {
      int gr = row0 + wr * 64 + mi * 16 + rsub + j;
      if (gr < N) {
        float rs = rowscale ? rowscale[gr] : 1.0f;
#pragma unroll
        for (int ni = 0; ni < 4; ++ni) {
          int c = cbase + ni * 16;
          float v = acc[mi][ni][j] * rs;
          if (bias) v += bias[c];
          if (do_relu) v = fmaxf(v, 0.f);
          out[(size_t)gr * HID + c] = (_Float16)v;
        }
      }
    }
  }
}

// ---------------- sparse aggregation: 4 rows per wave-instruction, 16 edges in flight ----------------

__global__ __launch_bounds__(256) void agg_pad(const _Float16* __restrict__ g,
                                               const int* __restrict__ cnt,
                                               const int* __restrict__ colpad,
                                               const float* __restrict__ dinv,
                                               const float* __restrict__ bias,
                                               _Float16* __restrict__ out, int N) {
  int node = blockIdx.x * 4 + (threadIdx.x >> 6);
  if (node >= N) return;
  const int lane = threadIdx.x & 63;
  const int es = lane >> 4;   // edge slot 0..3
  const int ch = lane & 15;   // 16-byte chunk 0..15
  const int deg = cnt[node];
  const int* __restrict__ row = colpad + (size_t)node * 64;

  float acc[8] = {0.f, 0.f, 0.f, 0.f, 0.f, 0.f, 0.f, 0.f};
  int e0 = 0;
  for (; e0 + 16 <= deg; e0 += 16) {
    int i0 = row[e0 + es];
    int i1 = row[e0 + 4 + es];
    int i2 = row[e0 + 8 + es];
    int i3 = row[e0 + 12 + es];
    half8 v0 = *(const half8*)(g + (size_t)i0 * HID + ch * 8);
    half8 v1 = *(const half8*)(g + (size_t)i1 * HID + ch * 8);
    half8 v2 = *(const half8*)(g + (size_t)i2 * HID + ch * 8);
    half8 v3 = *(const half8*)(g + (size_t)i3 * HID + ch * 8);
#pragma unroll
    for (int j = 0; j < 8; ++j)
      acc[j] += ((float)v0[j] + (float)v1[j]) + ((float)v2[j] + (float)v3[j]);
  }
  for (; e0 + 4 <= deg; e0 += 4) {
    int i0 = row[e0 + es];
    half8 v0 = *(const half8*)(g + (size_t)i0 * HID + ch * 8);
#pragma unroll
    for (int j = 0; j < 8; ++j) acc[j] += (float)v0[j];
  }
  const int rem = deg - e0;   // 0..3
  float selfw = 1.0f;
  if (rem > 0) {
    int i0 = (es < rem) ? row[e0 + es] : node;  // pad slots gather the self row
    half8 v0 = *(const half8*)(g + (size_t)i0 * HID + ch * 8);
#pragma unroll
    for (int j = 0; j < 8; ++j) acc[j] += (float)v0[j];
    selfw = 1.0f - (float)(4 - rem);  // compensate the (4-rem) extra self rows
  }

#pragma unroll
  for (int j = 0; j < 8; ++j) {
    acc[j] += __shfl_xor(acc[j], 16, 64);
    acc[j] += __shfl_xor(acc[j], 32, 64);
  }

  if (lane < 16) {
    half8 sv = *(const half8*)(g + (size_t)node * HID + ch * 8);
    const float di = dinv[node];
    half8 o;
#pragma unroll
    for (int j = 0; j < 8; ++j) {
      float v = di * (acc[j] + selfw * (float)sv[j]) + bias[ch * 8 + j];
      o[j] = (_Float16)fmaxf(v, 0.f);
    }
    *(half8*)(out + (size_t)node * HID + ch * 8) = o;
  }
}

// ---------------- final GEMM (MFMA): logits[N][40] = h[N][128] @ Wl[40][128]^T + bl ----------------

__global__ __launch_bounds__(256) void gemm40_mfma(const _Float16* __restrict__ h,
                                                   const float* __restrict__ Wl,
                                                   const float* __restrict__ bl,
                                                   float* __restrict__ out, int N) {
  __shared__ __align__(16) _Float16 wlds[48][136];

  const int tid = threadIdx.x;
  const int lane = tid & 63;
  const int wave = tid >> 6;
  const int row0 = blockIdx.x * 128;

#pragma unroll
  for (int i = 0; i < 6; ++i) {
    int idx4 = tid + i * 256;
    int c = idx4 >> 5;
    int ko = (idx4 & 31) * 4;
    float4 v = make_float4(0.f, 0.f, 0.f, 0.f);
    if (c < 40) v = *(const float4*)(Wl + (size_t)c * HID + ko);
    half4v hv;
    hv[0] = (_Float16)v.x; hv[1] = (_Float16)v.y;
    hv[2] = (_Float16)v.z; hv[3] = (_Float16)v.w;
    *(half4v*)&wlds[c][ko] = hv;
  }
  __syncthreads();

  f32x4 acc[2][3] = {};
  const int arow_in = lane & 15;
  const int kq = lane >> 4;

#pragma unroll
  for (int ks = 0; ks < 4; ++ks) {
    half8 a[2], b[3];
#pragma unroll
    for (int mi = 0; mi < 2; ++mi) {
      int gr = row0 + wave * 32 + mi * 16 + arow_in;
      if (gr >= N) gr = N - 1;
      a[mi] = *(const half8*)(h + (size_t)gr * HID + ks * 32 + kq * 8);
    }
#pragma unroll
    for (int ni = 0; ni < 3; ++ni) {
      int c = ni * 16 + arow_in;
      b[ni] = *(const half8*)&wlds[c][ks * 32 + kq * 8];
    }
#pragma unroll
    for (int mi = 0; mi < 2; ++mi)
#pragma unroll
      for (int ni = 0; ni < 3; ++ni)
        acc[mi][ni] = __builtin_amdgcn_mfma_f32_16x16x32_f16(a[mi], b[ni], acc[mi][ni], 0, 0, 0);
  }

  const int rsub = (lane >> 4) * 4;
#pragma unroll
  for (int ni = 0; ni < 3; ++ni) {
    int col = ni * 16 + (lane & 15);
    if (col >= 40) continue;
    float bv = bl[col];
#pragma unroll
    for (int mi = 0; mi < 2; ++mi) {
#pragma unroll
      for (int j = 0; j < 4; ++j) {
        int gr = row0 + wave * 32 + mi * 16 + rsub + j;
        if (gr < N) out[(size_t)gr * 40 + col] = acc[mi][ni][j] + bv;
      }
    }
  }
}

// ---------------- launch ----------------

extern "C" void kernel_launch(void* const* d_in, const int* in_sizes, int n_in,
                              void* d_out, int out_size, void* d_ws, size_t ws_size,
                              hipStream_t stream) {
  const float* x = (const float*)d_in[0];
  const int* ei = (const int*)d_in[1];
  const float* W0 = (const float*)d_in[2];
  const float* b0 = (const float*)d_in[3];
  const float* Wc = (const float*)d_in[4];
  const float* bc = (const float*)d_in[5];
  const float* Wl = (const float*)d_in[6];
  const float* bl = (const float*)d_in[7];
  float* out = (float*)d_out;

  const int N = in_sizes[0] / 512;
  const int E = in_sizes[1] / 2;
  const int NB = (N + (1 << BSHIFT) - 1) >> BSHIFT;  // 98 for N=100000

  char* ws = (char*)d_ws;
  size_t off = 0;
  auto alloc = [&](size_t bytes) -> char* {
    char* p = ws + off;
    off += (bytes + 511) & ~(size_t)511;
    return p;
  };
  float* dinv = (float*)alloc((size_t)N * 4);
  int* cnt = (int*)alloc((size_t)N * 4);
  int* gcur = (int*)alloc(128 * 4);
  int* colpad = (int*)alloc((size_t)N * 64 * 4);
  int2* bbuf = (int2*)alloc((size_t)NB * BCAP * 8);
  _Float16* xh = (_Float16*)alloc((size_t)N * 512 * 2);
  _Float16* hA = (_Float16*)alloc((size_t)N * HID * 2);
  _Float16* hB = (_Float16*)alloc((size_t)N * HID * 2);
  _Float16* hG = (_Float16*)alloc((size_t)N * HID * 2);
  _Float16* W0h = (_Float16*)alloc((size_t)HID * 512 * 2);
  _Float16* Wch = (_Float16*)alloc((size_t)3 * HID * HID * 2);

  const int nb_g = (N + 127) / 128;

  zero_i32<<<1, 256, 0, stream>>>(gcur, 128);
  bin_edges<<<512, 256, 0, stream>>>(ei, gcur, bbuf, E, NB);
  scatter_pad<<<NB, 256, 0, stream>>>(bbuf, gcur, colpad, cnt, dinv, N);

  const int nw0 = HID * 512, nwc = 3 * HID * HID;
  cvt_w2<<<(nw0 + nwc + 255) / 256, 256, 0, stream>>>(W0, nw0, Wc, nwc, W0h, Wch);
  cvt_x<<<2048, 256, 0, stream>>>(x, xh, N * 64);

  // input layer: hA = relu(xh @ W0^T + b0)
  gemm_mfma<512><<<nb_g, 256, 0, stream>>>(xh, W0h, b0, nullptr, hA, N, 1);

  _Float16* bufs[2] = {hA, hB};
  int cur = 0;
  for (int l = 0; l < 3; ++l) {
    gemm_mfma<128><<<nb_g, 256, 0, stream>>>(bufs[cur], Wch + (size_t)l * HID * HID,
                                             nullptr, dinv, hG, N, 0);
    agg_pad<<<(N + 3) / 4, 256, 0, stream>>>(hG, cnt, colpad, dinv, bc + (size_t)l * HID,
                                             bufs[1 - cur], N);
    cur = 1 - cur;
  }

  gemm40_mfma<<<nb_g, 256, 0, stream>>>(bufs[cur], Wl, bl, out, N);
}

// Round 9
// 393.808 us; speedup vs baseline: 1.0893x; 1.0893x over previous
//
#include <hip/hip_runtime.h>

#define HID 128
#define BSHIFT 10            // 1024 dst-nodes per bucket
#define BCAP 20480           // bucket capacity (mean 16.3K, sigma ~127 -> 32 sigma)

typedef _Float16 half8 __attribute__((ext_vector_type(8)));
typedef _Float16 half4v __attribute__((ext_vector_type(4)));
typedef float f32x4 __attribute__((ext_vector_type(4)));

// async global->LDS, 16B per lane; LDS dest = wave-uniform base + lane*16
#define GLDS16(gp, lp)                                                        \
  __builtin_amdgcn_global_load_lds(                                           \
      (const __attribute__((address_space(1))) void*)(gp),                    \
      (__attribute__((address_space(3))) void*)(lp), 16, 0, 0)

// ---------------- graph build: two-pass binned scatter ----------------

__global__ __launch_bounds__(256) void zero_i32(int* __restrict__ p, int n) {
  int i = blockIdx.x * 256 + threadIdx.x;
  if (i < n) p[i] = 0;
}

__global__ __launch_bounds__(256) void bin_edges(const int* __restrict__ ei,
                                                 int* __restrict__ gcur,
                                                 int2* __restrict__ buf,
                                                 int E, int NB) {
  __shared__ int bcnt[128];
  __shared__ int bbase[128];
  const int tid = threadIdx.x;

  for (int chunk = blockIdx.x * 2048; chunk < E; chunk += gridDim.x * 2048) {
    if (tid < NB) bcnt[tid] = 0;
    __syncthreads();
    int s[8], d[8], slot[8], b[8];
#pragma unroll
    for (int j = 0; j < 8; ++j) {
      int e = chunk + tid + j * 256;
      if (e < E) {
        s[j] = ei[e];
        d[j] = ei[E + e];
        b[j] = d[j] >> BSHIFT;
        slot[j] = atomicAdd(&bcnt[b[j]], 1);
      } else {
        b[j] = -1;
      }
    }
    __syncthreads();
    if (tid < NB && bcnt[tid] > 0) bbase[tid] = atomicAdd(&gcur[tid], bcnt[tid]);
    __syncthreads();
#pragma unroll
    for (int j = 0; j < 8; ++j) {
      if (b[j] >= 0) {
        int pos = bbase[b[j]] + slot[j];
        if (pos < BCAP) buf[(size_t)b[j] * BCAP + pos] = make_int2(s[j], d[j]);
      }
    }
    __syncthreads();
  }
}

__global__ __launch_bounds__(256) void scatter_pad(const int2* __restrict__ buf,
                                                   const int* __restrict__ gcur,
                                                   int* __restrict__ colpad,
                                                   int* __restrict__ cnt,
                                                   float* __restrict__ dinv, int N) {
  __shared__ int lcnt[1 << BSHIFT];
  const int b = blockIdx.x;
  const int base = b << BSHIFT;
  const int tid = threadIdx.x;
  for (int i = tid; i < (1 << BSHIFT); i += 256) lcnt[i] = 0;
  __syncthreads();

  int ne = gcur[b];
  if (ne > BCAP) ne = BCAP;
  const int2* __restrict__ bb = buf + (size_t)b * BCAP;
  for (int i = tid; i < ne; i += 256) {
    int2 p = bb[i];
    int pos = atomicAdd(&lcnt[p.y - base], 1);
    if (pos < 64) colpad[(size_t)p.y * 64 + pos] = p.x;
  }
  __syncthreads();
  for (int i = tid; i < (1 << BSHIFT); i += 256) {
    int n = base + i;
    if (n < N) {
      int c = lcnt[i];
      cnt[n] = c;
      dinv[n] = rsqrtf((float)(c + 1));
    }
  }
}

// ---------------- weight convert fp32 -> f16 ----------------

__global__ __launch_bounds__(256) void cvt_w2(const float* __restrict__ a, int na,
                                              const float* __restrict__ b, int nb,
                                              _Float16* __restrict__ oa,
                                              _Float16* __restrict__ ob) {
  int i = blockIdx.x * 256 + threadIdx.x;
  if (i < na) oa[i] = (_Float16)a[i];
  else if (i < na + nb) ob[i - na] = (_Float16)b[i - na];
}

// ---------------- MFMA GEMM via global_load_lds (m97 structure) ----------------
// out[N][128] = A[N][K] @ W[128][K]^T.  A fp32 (CONVA: kept fp32 in LDS,
// converted at fragment read) or f16.  W f16.  Epilogue scale/bias/relu.
// LDS linear-dest (glds), bank-swizzle via pre-swizzled GLOBAL source chunk
// (csw = c ^ (r&7)) + matching XOR on the read side.

template <int K, bool CONVA>
__global__ __launch_bounds__(256) void gemm_glds(const void* __restrict__ Av,
                                                 const _Float16* __restrict__ Wh,
                                                 const float* __restrict__ bias,
                                                 const float* __restrict__ rowscale,
                                                 _Float16* __restrict__ out,
                                                 int N, int do_relu) {
  constexpr int ABYTES = CONVA ? 128 * 64 * 4 : 128 * 64 * 2;
  __shared__ __align__(16) char As[ABYTES];
  __shared__ __align__(16) char Bs[128 * 64 * 2];

  const int tid = threadIdx.x;
  const int lane = tid & 63;
  const int wave = tid >> 6;
  const int wr = wave >> 1, wc = wave & 1;  // 2x2 wave grid, each 64x64
  const int row0 = blockIdx.x * 128;

  const float* Af = (const float*)Av;
  const _Float16* Ah = (const _Float16*)Av;

  // ---- staging descriptors (constant across k-steps) ----
  // A, CONVA(fp32, 256B/row): 8 instrs x 4 rows/wave; lane: r=lane>>4, ch16=lane&15
  // A, f16(128B/row):         4 instrs x 8 rows/wave; lane: r=lane>>3, ch16=lane&7
  // B, f16:                   4 instrs x 8 rows/wave
  const char* aptr[8];
  int abase[8];
  int nA;
  if constexpr (CONVA) {
    nA = 8;
#pragma unroll
    for (int i = 0; i < 8; ++i) {
      int r = wave * 32 + i * 4 + (lane >> 4);
      int gr = row0 + r; if (gr >= N) gr = N - 1;
      int csw = (lane & 15) ^ (r & 7);
      aptr[i] = (const char*)(Af + (size_t)gr * K + csw * 4);
      abase[i] = (wave * 32 + i * 4) * 256;
    }
  } else {
    nA = 4;
#pragma unroll
    for (int i = 0; i < 4; ++i) {
      int r = wave * 32 + i * 8 + (lane >> 3);
      int gr = row0 + r; if (gr >= N) gr = N - 1;
      int csw = (lane & 7) ^ (r & 7);
      aptr[i] = (const char*)(Ah + (size_t)gr * K + csw * 8);
      abase[i] = (wave * 32 + i * 8) * 128;
    }
  }
  const char* bptr[4];
  int bbase[4];
#pragma unroll
  for (int i = 0; i < 4; ++i) {
    int r = wave * 32 + i * 8 + (lane >> 3);
    int csw = (lane & 7) ^ (r & 7);
    bptr[i] = (const char*)(Wh + (size_t)r * K + csw * 8);
    bbase[i] = (wave * 32 + i * 8) * 128;
  }

  f32x4 acc[4][4] = {};

  for (int k0 = 0; k0 < K; k0 += 64) {
    // issue async stage of tile k0 (prev compute finished at loop-end barrier)
    if constexpr (CONVA) {
#pragma unroll
      for (int i = 0; i < 8; ++i) GLDS16(aptr[i] + (size_t)k0 * 4, As + abase[i]);
    } else {
#pragma unroll
      for (int i = 0; i < 4; ++i) GLDS16(aptr[i] + (size_t)k0 * 2, As + abase[i]);
    }
#pragma unroll
    for (int i = 0; i < 4; ++i) GLDS16(bptr[i] + (size_t)k0 * 2, Bs + bbase[i]);
    __syncthreads();  // drains vmcnt -> LDS tile complete

#pragma unroll
    for (int ks = 0; ks < 2; ++ks) {
      half8 a[4], b[4];
#pragma unroll
      for (int mi = 0; mi < 4; ++mi) {
        int r = wr * 64 + mi * 16 + (lane & 15);
        int q = ks * 4 + (lane >> 4);     // 8-element k-group 0..7
        if constexpr (CONVA) {
          int c0 = (2 * q) ^ (r & 7);
          int c1 = (2 * q + 1) ^ (r & 7);
          f32x4 f0 = *(const f32x4*)(As + (r << 8) + (c0 << 4));
          f32x4 f1 = *(const f32x4*)(As + (r << 8) + (c1 << 4));
          half8 h;
          h[0] = (_Float16)f0[0]; h[1] = (_Float16)f0[1];
          h[2] = (_Float16)f0[2]; h[3] = (_Float16)f0[3];
          h[4] = (_Float16)f1[0]; h[5] = (_Float16)f1[1];
          h[6] = (_Float16)f1[2]; h[7] = (_Float16)f1[3];
          a[mi] = h;
        } else {
          a[mi] = *(const half8*)(As + (r << 7) + (((q ^ (r & 7))) << 4));
        }
      }
#pragma unroll
      for (int ni = 0; ni < 4; ++ni) {
        int c = wc * 64 + ni * 16 + (lane & 15);
        int q = ks * 4 + (lane >> 4);
        b[ni] = *(const half8*)(Bs + ((c << 7) | ((q ^ (c & 7)) << 4)));
      }
#pragma unroll
      for (int mi = 0; mi < 4; ++mi)
#pragma unroll
        for (int ni = 0; ni < 4; ++ni)
          acc[mi][ni] = __builtin_amdgcn_mfma_f32_16x16x32_f16(a[mi], b[ni], acc[mi][ni], 0, 0, 0);
    }
    __syncthreads();  // all waves done reading before next stage overwrites
  }

  // epilogue: col = lane&15 (+16*ni+64*wc), row = (lane>>4)*4 + j (+16*mi+64*wr)
  const int cbase = wc * 64 + (lane & 15);
  const int rsub = (lane >> 4) * 4;
#pragma unroll
  for (int mi = 0; mi < 4; ++mi) {
#pragma unroll
    for (int j = 0; j < 4; ++j) {
      int gr = row0 + wr * 64 + mi * 16 + rsub + j;
      if (gr < N) {
        float rs = rowscale ? rowscale[gr] : 1.0f;
#pragma unroll
        for (int ni = 0; ni < 4; ++ni) {
          int c = cbase + ni * 16;
          float v = acc[mi][ni][j] * rs;
          if (bias) v += bias[c];
          if (do_relu) v = fmaxf(v, 0.f);
          out[(size_t)gr * HID + c] = (_Float16)v;
        }
      }
    }
  }
}

// ---------------- sparse aggregation: 4 rows per wave-instruction ----------------

__global__ __launch_bounds__(256) void agg_pad(const _Float16* __restrict__ g,
                                               const int* __restrict__ cnt,
                                               const int* __restrict__ colpad,
                                               const float* __restrict__ dinv,
                                               const float* __restrict__ bias,
                                               _Float16* __restrict__ out, int N) {
  int node = blockIdx.x * 4 + (threadIdx.x >> 6);
  if (node >= N) return;
  const int lane = threadIdx.x & 63;
  const int es = lane >> 4;   // edge slot 0..3
  const int ch = lane & 15;   // 16-byte chunk 0..15
  const int deg = cnt[node];
  const int* __restrict__ row = colpad + (size_t)node * 64;

  float acc[8] = {0.f, 0.f, 0.f, 0.f, 0.f, 0.f, 0.f, 0.f};
  int e0 = 0;
  for (; e0 + 16 <= deg; e0 += 16) {
    int i0 = row[e0 + es];
    int i1 = row[e0 + 4 + es];
    int i2 = row[e0 + 8 + es];
    int i3 = row[e0 + 12 + es];
    half8 v0 = *(const half8*)(g + (size_t)i0 * HID + ch * 8);
    half8 v1 = *(const half8*)(g + (size_t)i1 * HID + ch * 8);
    half8 v2 = *(const half8*)(g + (size_t)i2 * HID + ch * 8);
    half8 v3 = *(const half8*)(g + (size_t)i3 * HID + ch * 8);
#pragma unroll
    for (int j = 0; j < 8; ++j)
      acc[j] += ((float)v0[j] + (float)v1[j]) + ((float)v2[j] + (float)v3[j]);
  }
  for (; e0 + 4 <= deg; e0 += 4) {
    int i0 = row[e0 + es];
    half8 v0 = *(const half8*)(g + (size_t)i0 * HID + ch * 8);
#pragma unroll
    for (int j = 0; j < 8; ++j) acc[j] += (float)v0[j];
  }
  const int rem = deg - e0;   // 0..3
  float selfw = 1.0f;
  if (rem > 0) {
    int i0 = (es < rem) ? row[e0 + es] : node;  // pad slots gather the self row
    half8 v0 = *(const half8*)(g + (size_t)i0 * HID + ch * 8);
#pragma unroll
    for (int j = 0; j < 8; ++j) acc[j] += (float)v0[j];
    selfw = 1.0f - (float)(4 - rem);  // compensate the (4-rem) extra self rows
  }

#pragma unroll
  for (int j = 0; j < 8; ++j) {
    acc[j] += __shfl_xor(acc[j], 16, 64);
    acc[j] += __shfl_xor(acc[j], 32, 64);
  }

  if (lane < 16) {
    half8 sv = *(const half8*)(g + (size_t)node * HID + ch * 8);
    const float di = dinv[node];
    half8 o;
#pragma unroll
    for (int j = 0; j < 8; ++j) {
      float v = di * (acc[j] + selfw * (float)sv[j]) + bias[ch * 8 + j];
      o[j] = (_Float16)fmaxf(v, 0.f);
    }
    *(half8*)(out + (size_t)node * HID + ch * 8) = o;
  }
}

// ---------------- final GEMM (MFMA): logits[N][40] = h[N][128] @ Wl[40][128]^T + bl ----------------

__global__ __launch_bounds__(256) void gemm40_mfma(const _Float16* __restrict__ h,
                                                   const float* __restrict__ Wl,
                                                   const float* __restrict__ bl,
                                                   float* __restrict__ out, int N) {
  __shared__ __align__(16) _Float16 wlds[48][136];

  const int tid = threadIdx.x;
  const int lane = tid & 63;
  const int wave = tid >> 6;
  const int row0 = blockIdx.x * 128;

#pragma unroll
  for (int i = 0; i < 6; ++i) {
    int idx4 = tid + i * 256;
    int c = idx4 >> 5;
    int ko = (idx4 & 31) * 4;
    float4 v = make_float4(0.f, 0.f, 0.f, 0.f);
    if (c < 40) v = *(const float4*)(Wl + (size_t)c * HID + ko);
    half4v hv;
    hv[0] = (_Float16)v.x; hv[1] = (_Float16)v.y;
    hv[2] = (_Float16)v.z; hv[3] = (_Float16)v.w;
    *(half4v*)&wlds[c][ko] = hv;
  }
  __syncthreads();

  f32x4 acc[2][3] = {};
  const int arow_in = lane & 15;
  const int kq = lane >> 4;

#pragma unroll
  for (int ks = 0; ks < 4; ++ks) {
    half8 a[2], b[3];
#pragma unroll
    for (int mi = 0; mi < 2; ++mi) {
      int gr = row0 + wave * 32 + mi * 16 + arow_in;
      if (gr >= N) gr = N - 1;
      a[mi] = *(const half8*)(h + (size_t)gr * HID + ks * 32 + kq * 8);
    }
#pragma unroll
    for (int ni = 0; ni < 3; ++ni) {
      int c = ni * 16 + arow_in;
      b[ni] = *(const half8*)&wlds[c][ks * 32 + kq * 8];
    }
#pragma unroll
    for (int mi = 0; mi < 2; ++mi)
#pragma unroll
      for (int ni = 0; ni < 3; ++ni)
        acc[mi][ni] = __builtin_amdgcn_mfma_f32_16x16x32_f16(a[mi], b[ni], acc[mi][ni], 0, 0, 0);
  }

  const int rsub = (lane >> 4) * 4;
#pragma unroll
  for (int ni = 0; ni < 3; ++ni) {
    int col = ni * 16 + (lane & 15);
    if (col >= 40) continue;
    float bv = bl[col];
#pragma unroll
    for (int mi = 0; mi < 2; ++mi) {
#pragma unroll
      for (int j = 0; j < 4; ++j) {
        int gr = row0 + wave * 32 + mi * 16 + rsub + j;
        if (gr < N) out[(size_t)gr * 40 + col] = acc[mi][ni][j] + bv;
      }
    }
  }
}

// ---------------- launch ----------------

extern "C" void kernel_launch(void* const* d_in, const int* in_sizes, int n_in,
                              void* d_out, int out_size, void* d_ws, size_t ws_size,
                              hipStream_t stream) {
  const float* x = (const float*)d_in[0];
  const int* ei = (const int*)d_in[1];
  const float* W0 = (const float*)d_in[2];
  const float* b0 = (const float*)d_in[3];
  const float* Wc = (const float*)d_in[4];
  const float* bc = (const float*)d_in[5];
  const float* Wl = (const float*)d_in[6];
  const float* bl = (const float*)d_in[7];
  float* out = (float*)d_out;

  const int N = in_sizes[0] / 512;
  const int E = in_sizes[1] / 2;
  const int NB = (N + (1 << BSHIFT) - 1) >> BSHIFT;  // 98 for N=100000

  char* ws = (char*)d_ws;
  size_t off = 0;
  auto alloc = [&](size_t bytes) -> char* {
    char* p = ws + off;
    off += (bytes + 511) & ~(size_t)511;
    return p;
  };
  float* dinv = (float*)alloc((size_t)N * 4);
  int* cnt = (int*)alloc((size_t)N * 4);
  int* gcur = (int*)alloc(128 * 4);
  int* colpad = (int*)alloc((size_t)N * 64 * 4);
  int2* bbuf = (int2*)alloc((size_t)NB * BCAP * 8);
  _Float16* hA = (_Float16*)alloc((size_t)N * HID * 2);
  _Float16* hB = (_Float16*)alloc((size_t)N * HID * 2);
  _Float16* hG = (_Float16*)alloc((size_t)N * HID * 2);
  _Float16* W0h = (_Float16*)alloc((size_t)HID * 512 * 2);
  _Float16* Wch = (_Float16*)alloc((size_t)3 * HID * HID * 2);

  const int nb_g = (N + 127) / 128;

  zero_i32<<<1, 256, 0, stream>>>(gcur, 128);
  bin_edges<<<512, 256, 0, stream>>>(ei, gcur, bbuf, E, NB);
  scatter_pad<<<NB, 256, 0, stream>>>(bbuf, gcur, colpad, cnt, dinv, N);

  const int nw0 = HID * 512, nwc = 3 * HID * HID;
  cvt_w2<<<(nw0 + nwc + 255) / 256, 256, 0, stream>>>(W0, nw0, Wc, nwc, W0h, Wch);

  // input layer: hA = relu(x @ W0^T + b0)   (A read as fp32, converted at frag read)
  gemm_glds<512, true><<<nb_g, 256, 0, stream>>>(x, W0h, b0, nullptr, hA, N, 1);

  _Float16* bufs[2] = {hA, hB};
  int cur = 0;
  for (int l = 0; l < 3; ++l) {
    gemm_glds<128, false><<<nb_g, 256, 0, stream>>>(bufs[cur], Wch + (size_t)l * HID * HID,
                                                    nullptr, dinv, hG, N, 0);
    agg_pad<<<(N + 3) / 4, 256, 0, stream>>>(hG, cnt, colpad, dinv, bc + (size_t)l * HID,
                                             bufs[1 - cur], N);
    cur = 1 - cur;
  }

  gemm40_mfma<<<nb_g, 256, 0, stream>>>(bufs[cur], Wl, bl, out, N);
}